// Round 1
// baseline (689.502 us; speedup 1.0000x reference)
//
#include <hip/hip_runtime.h>
#include <hip/hip_bf16.h>

#define D_ 768
#define W_ 128
#define T_ 64
#define S_ 256
#define H_ 12
#define BT_ 512

// K1: q[bt][d] = mean over 16x16 patch of x[b,d,:,:]
__global__ __launch_bounds__(256) void k_q(const float* __restrict__ x, float* __restrict__ q) {
  const int bd = blockIdx.x;              // b*D + d
  const int tid = threadIdx.x;
  const float4* xp = (const float4*)(x + (size_t)bd * (W_*W_));
  float acc[8] = {0,0,0,0,0,0,0,0};
  #pragma unroll
  for (int k = 0; k < 16; ++k) {
    float4 v = xp[k*256 + tid];           // coalesced: lane-contiguous
    acc[k>>1] += (v.x + v.y) + (v.z + v.w);   // ti = k>>1 for this mapping
  }
  __shared__ float part[256][9];
  #pragma unroll
  for (int i = 0; i < 8; ++i) part[tid][i] = acc[i];
  __syncthreads();
  if (tid < 64) {
    const int ti = tid >> 3, tj = tid & 7;
    float s = 0.f;
    #pragma unroll
    for (int m = 0; m < 8; ++m)
      #pragma unroll
      for (int n = 0; n < 4; ++n)
        s += part[m*32 + tj*4 + n][ti];
    const int b = bd / D_, d = bd - b*D_;
    q[(size_t)(b*T_ + tid)*D_ + d] = s * (1.0f/256.0f);
  }
}

// K2: qp = q @ Wq.T + bq ; qk[h][:] = (sum_i qp[h*64+i]*Wk[h*64+i][:]) / 8
__global__ __launch_bounds__(256) void k_qk(const float* __restrict__ q,
                                            const float* __restrict__ ipw,
                                            const float* __restrict__ ipb,
                                            float* __restrict__ qkout) {
  const int bt0 = blockIdx.x * 4;
  const int tid = threadIdx.x;
  __shared__ float qs[4][D_];
  __shared__ float qps[4][D_];
  #pragma unroll
  for (int g = 0; g < 4; ++g)
    #pragma unroll
    for (int c = 0; c < 3; ++c)
      qs[g][c*256 + tid] = q[(size_t)(bt0+g)*D_ + c*256 + tid];
  __syncthreads();
  #pragma unroll
  for (int jj = 0; jj < 3; ++jj) {
    const int j = jj*256 + tid;
    const float* wr = ipw + (size_t)j * D_;   // Wq row j
    float a0=0,a1=0,a2=0,a3=0;
    for (int dd = 0; dd < D_; dd += 4) {
      const float4 wv = *(const float4*)(wr + dd);
      const float4 q0 = *(const float4*)(&qs[0][dd]);
      const float4 q1 = *(const float4*)(&qs[1][dd]);
      const float4 q2 = *(const float4*)(&qs[2][dd]);
      const float4 q3 = *(const float4*)(&qs[3][dd]);
      a0 += wv.x*q0.x + wv.y*q0.y + wv.z*q0.z + wv.w*q0.w;
      a1 += wv.x*q1.x + wv.y*q1.y + wv.z*q1.z + wv.w*q1.w;
      a2 += wv.x*q2.x + wv.y*q2.y + wv.z*q2.z + wv.w*q2.w;
      a3 += wv.x*q3.x + wv.y*q3.y + wv.z*q3.z + wv.w*q3.w;
    }
    const float bqj = ipb[j];
    qps[0][j] = a0 + bqj; qps[1][j] = a1 + bqj;
    qps[2][j] = a2 + bqj; qps[3][j] = a3 + bqj;
  }
  __syncthreads();
  const float* Wk = ipw + (size_t)D_ * D_;
  float acc[4][3];
  for (int h = 0; h < H_; ++h) {
    #pragma unroll
    for (int g = 0; g < 4; ++g) { acc[g][0]=0.f; acc[g][1]=0.f; acc[g][2]=0.f; }
    for (int r = h*64; r < h*64+64; ++r) {
      const float* wr = Wk + (size_t)r * D_;
      const float w0 = wr[tid], w1 = wr[256+tid], w2 = wr[512+tid];
      #pragma unroll
      for (int g = 0; g < 4; ++g) {
        const float qv = qps[g][r];
        acc[g][0] += qv*w0; acc[g][1] += qv*w1; acc[g][2] += qv*w2;
      }
    }
    #pragma unroll
    for (int g = 0; g < 4; ++g)
      #pragma unroll
      for (int c = 0; c < 3; ++c)
        qkout[((size_t)(bt0+g)*H_ + h)*D_ + c*256 + tid] = acc[g][c] * 0.125f;
  }
}

// K3: per (b,t): scores -> softmax -> weighted sum of kv rows
__global__ __launch_bounds__(256) void k_attn(const float* __restrict__ x,
                                              const float* __restrict__ qkin,
                                              float* __restrict__ wout) {
  const int bt = blockIdx.x;
  const int b = bt >> 6, t = bt & 63;
  const int ti = t >> 3, tj = t & 7;
  const int tid = threadIdx.x;
  __shared__ float qkl[H_*D_];   // 36 KB
  __shared__ float sc[H_][S_];   // 12 KB
  const float* xb = x + (size_t)b*D_*W_*W_ + ti*16*W_ + tj*16;

  { // load qk block
    const float4* src = (const float4*)(qkin + (size_t)bt*H_*D_);
    float4* dst = (float4*)qkl;
    #pragma unroll
    for (int k = 0; k < 9; ++k) dst[k*256 + tid] = src[k*256 + tid];
  }
  __syncthreads();

  // phase 3: scores[h][s=tid] = qk_h . kv_s   (kv row s = channels 3s..3s+2 of patch)
  float acc[H_];
  #pragma unroll
  for (int h = 0; h < H_; ++h) acc[h] = 0.f;
  #pragma unroll
  for (int c = 0; c < 3; ++c) {
    const float* chp = xb + (size_t)(3*tid + c)*(W_*W_);
    for (int blk = 0; blk < 8; ++blk) {
      float4 v[8];
      #pragma unroll
      for (int u = 0; u < 8; ++u) {
        const int pg = blk*8 + u;                // float4 index in 16x16 patch
        v[u] = *(const float4*)(chp + (pg>>2)*W_ + (pg&3)*4);
      }
      const int dbase = c*256 + blk*32;
      #pragma unroll
      for (int h = 0; h < H_; ++h) {
        const float4* qh = (const float4*)(qkl + h*D_ + dbase);
        float s0 = 0.f;
        #pragma unroll
        for (int u = 0; u < 8; ++u) {
          const float4 qv = qh[u];
          s0 += qv.x*v[u].x + qv.y*v[u].y + qv.z*v[u].z + qv.w*v[u].w;
        }
        acc[h] += s0;
      }
    }
  }
  #pragma unroll
  for (int h = 0; h < H_; ++h) sc[h][tid] = acc[h];
  __syncthreads();

  // phase 4: softmax over s, per wave: 3 heads each (head fits in one wave)
  {
    const int wv = tid >> 6, lane = tid & 63;
    #pragma unroll
    for (int hh = 0; hh < 3; ++hh) {
      const int h = wv*3 + hh;
      float4 v = *(const float4*)(&sc[h][lane*4]);
      float m = fmaxf(fmaxf(v.x, v.y), fmaxf(v.z, v.w));
      #pragma unroll
      for (int off = 32; off > 0; off >>= 1) m = fmaxf(m, __shfl_xor(m, off));
      const float e0 = __expf(v.x - m), e1 = __expf(v.y - m),
                  e2 = __expf(v.z - m), e3 = __expf(v.w - m);
      float ss = (e0+e1)+(e2+e3);
      #pragma unroll
      for (int off = 32; off > 0; off >>= 1) ss += __shfl_xor(ss, off);
      const float inv = 1.0f / ss;
      *(float4*)(&sc[h][lane*4]) = make_float4(e0*inv, e1*inv, e2*inv, e3*inv);
    }
  }
  __syncthreads();

  // phase 5: w[h][c*256 + p] = sum_s attn[h][s] * patch[3s+c][p], p = tid
  float wacc[H_][3];
  #pragma unroll
  for (int h = 0; h < H_; ++h) { wacc[h][0]=0.f; wacc[h][1]=0.f; wacc[h][2]=0.f; }
  const float* xp0 = xb + (tid>>4)*W_ + (tid&15);
  for (int s = 0; s < S_; ++s) {
    const float p0 = xp0[(size_t)(3*s+0)*(W_*W_)];
    const float p1 = xp0[(size_t)(3*s+1)*(W_*W_)];
    const float p2 = xp0[(size_t)(3*s+2)*(W_*W_)];
    #pragma unroll
    for (int h = 0; h < H_; ++h) {
      const float at = sc[h][s];
      wacc[h][0] += at*p0; wacc[h][1] += at*p1; wacc[h][2] += at*p2;
    }
  }
  float* wp = wout + (size_t)bt*H_*D_;
  #pragma unroll
  for (int h = 0; h < H_; ++h)
    #pragma unroll
    for (int c = 0; c < 3; ++c)
      wp[h*D_ + c*256 + tid] = wacc[h][c];
}

// K4a: ctx[bt][h*64+i] = sum_d w[bt][h][d] * Wv[h*64+i][d] + bv
__global__ __launch_bounds__(256) void k_ctx(const float* __restrict__ wbuf,
                                             const float* __restrict__ ipw,
                                             const float* __restrict__ ipb,
                                             float* __restrict__ ctx) {
  const int h = blockIdx.x >> 4;
  const int bt0 = (blockIdx.x & 15) * 32;
  const int tid = threadIdx.x;
  const float* Wv = ipw + (size_t)2*D_*D_ + (size_t)h*64*D_;
  __shared__ float wt[64][65];
  __shared__ float at[32][65];
  const int i = tid & 63, qw = tid >> 6;
  float acc[8] = {0,0,0,0,0,0,0,0};
  for (int dc = 0; dc < D_; dc += 64) {
    #pragma unroll
    for (int k = 0; k < 4; ++k) {
      const int idx = k*256 + tid;
      const int r = idx >> 4, c4 = idx & 15;
      *(float4*)&wt[r][c4*4] = *(const float4*)(Wv + (size_t)r*D_ + dc + c4*4);
    }
    #pragma unroll
    for (int k = 0; k < 2; ++k) {
      const int idx = k*256 + tid;
      const int r = idx >> 4, c4 = idx & 15;
      *(float4*)&at[r][c4*4] = *(const float4*)(wbuf + ((size_t)(bt0 + r)*H_ + h)*D_ + dc + c4*4);
    }
    __syncthreads();
    #pragma unroll
    for (int dd = 0; dd < 64; ++dd) {
      const float wv = wt[i][dd];
      #pragma unroll
      for (int k = 0; k < 8; ++k)
        acc[k] += at[qw + k*4][dd] * wv;
    }
    __syncthreads();
  }
  const float bvv = ipb[2*D_ + h*64 + i];
  #pragma unroll
  for (int k = 0; k < 8; ++k)
    ctx[(size_t)(bt0 + qw + k*4)*D_ + h*64 + i] = acc[k] + bvv;
}

// K4b: out[bt][j] = sum_e ctx[bt][e] * ow[j][e] + ob[j]
__global__ __launch_bounds__(256) void k_out(const float* __restrict__ ctx,
                                             const float* __restrict__ ow,
                                             const float* __restrict__ ob,
                                             float* __restrict__ out) {
  const int jt = blockIdx.x >> 4;
  const int bt0 = (blockIdx.x & 15) * 32;
  const int tid = threadIdx.x;
  const float* Wr = ow + (size_t)jt*64*D_;
  __shared__ float wt[64][65];
  __shared__ float at[32][65];
  const int i = tid & 63, qw = tid >> 6;
  float acc[8] = {0,0,0,0,0,0,0,0};
  for (int dc = 0; dc < D_; dc += 64) {
    #pragma unroll
    for (int k = 0; k < 4; ++k) {
      const int idx = k*256 + tid;
      const int r = idx >> 4, c4 = idx & 15;
      *(float4*)&wt[r][c4*4] = *(const float4*)(Wr + (size_t)r*D_ + dc + c4*4);
    }
    #pragma unroll
    for (int k = 0; k < 2; ++k) {
      const int idx = k*256 + tid;
      const int r = idx >> 4, c4 = idx & 15;
      *(float4*)&at[r][c4*4] = *(const float4*)(ctx + (size_t)(bt0 + r)*D_ + dc + c4*4);
    }
    __syncthreads();
    #pragma unroll
    for (int dd = 0; dd < 64; ++dd) {
      const float wv = wt[i][dd];
      #pragma unroll
      for (int k = 0; k < 8; ++k)
        acc[k] += at[qw + k*4][dd] * wv;
    }
    __syncthreads();
  }
  const float obv = ob[jt*64 + i];
  #pragma unroll
  for (int k = 0; k < 8; ++k)
    out[(size_t)(bt0 + qw + k*4)*D_ + jt*64 + i] = acc[k] + obv;
}

extern "C" void kernel_launch(void* const* d_in, const int* in_sizes, int n_in,
                              void* d_out, int out_size, void* d_ws, size_t ws_size,
                              hipStream_t stream) {
  const float* x   = (const float*)d_in[0];
  const float* ipw = (const float*)d_in[1];
  const float* ipb = (const float*)d_in[2];
  const float* ow  = (const float*)d_in[3];
  const float* ob  = (const float*)d_in[4];
  float* out = (float*)d_out;

  float* q    = (float*)d_ws;                    // BT*D            = 1.57 MB
  float* qkb  = q + (size_t)BT_*D_;              // BT*H*D          = 18.9 MB
  float* wb   = qkb + (size_t)BT_*H_*D_;         // BT*H*D          = 18.9 MB
  float* ctxb = wb + (size_t)BT_*H_*D_;          // BT*D            = 1.57 MB

  k_q   <<<dim3(8*D_), dim3(256), 0, stream>>>(x, q);
  k_qk  <<<dim3(128),  dim3(256), 0, stream>>>(q, ipw, ipb, qkb);
  k_attn<<<dim3(BT_),  dim3(256), 0, stream>>>(x, qkb, wb);
  k_ctx <<<dim3(192),  dim3(256), 0, stream>>>(wb, ipw, ipb, ctxb);
  k_out <<<dim3(192),  dim3(256), 0, stream>>>(ctxb, ow, ob, out);
}

// Round 2
// 614.659 us; speedup vs baseline: 1.1218x; 1.1218x over previous
//
#include <hip/hip_runtime.h>
#include <hip/hip_bf16.h>

#define D_ 768
#define W_ 128
#define T_ 64
#define S_ 256
#define H_ 12
#define BT_ 512

// Fused per-(b,t) kernel: pool -> qp=Wq q+bq -> qk=Wk_h^T qp/8 -> scores ->
// softmax -> weighted kv sum. Reads x from HBM exactly once (pool phase);
// score/wsum phases re-read the 786KB patch from L2/L3.
__global__ __launch_bounds__(256) void k_mega(const float* __restrict__ x,
                                              const float* __restrict__ ipw,
                                              const float* __restrict__ ipb,
                                              float* __restrict__ wout) {
  const int bt = blockIdx.x;
  const int b = bt >> 6, t = bt & 63;
  const int ti = t >> 3, tj = t & 7;
  const int tid = threadIdx.x;
  __shared__ float qkl[H_ * D_];   // 36 KB; sc[12][256] aliases front after scores
  __shared__ float qv[D_];         // 3 KB  pooled q
  __shared__ float qp[D_];         // 3 KB  q-projection
  const float* xb = x + (size_t)b*D_*W_*W_ + ti*16*W_ + tj*16;

  // ---- P1: pool (the one HBM pass over this block's patch) ----
  {
    const int ch0 = tid >> 2, col = tid & 3;
    #pragma unroll
    for (int cc = 0; cc < 12; ++cc) {
      const int ch = cc*64 + ch0;
      const float* p = xb + (size_t)ch*(W_*W_) + col*4;
      float s = 0.f;
      #pragma unroll
      for (int r = 0; r < 16; ++r) {
        const float4 v = *(const float4*)(p + r*W_);
        s += (v.x + v.y) + (v.z + v.w);
      }
      s += __shfl_xor(s, 1);
      s += __shfl_xor(s, 2);
      if (col == 0) qv[ch] = s * (1.0f/256.0f);
    }
  }
  __syncthreads();

  // ---- P2: qp[j] = bq[j] + qv . Wq[j][:] ----
  #pragma unroll
  for (int jj = 0; jj < 3; ++jj) {
    const int j = jj*256 + tid;
    const float* wr = ipw + (size_t)j * D_;
    float a = 0.f;
    for (int d = 0; d < D_; d += 4) {
      const float4 wv = *(const float4*)(wr + d);
      const float4 qd = *(const float4*)(&qv[d]);
      a += wv.x*qd.x + wv.y*qd.y + wv.z*qd.z + wv.w*qd.w;
    }
    qp[j] = a + ipb[j];
  }
  __syncthreads();

  // ---- P2b: qk[h][dd] = (sum_i qp[h*64+i] * Wk[h*64+i][dd]) * 0.125 ----
  {
    const float* Wk = ipw + (size_t)D_ * D_;
    #pragma unroll
    for (int h = 0; h < H_; ++h) {
      float a0 = 0.f, a1 = 0.f, a2 = 0.f;
      #pragma unroll 8
      for (int i = 0; i < 64; ++i) {
        const int r = h*64 + i;
        const float* wr = Wk + (size_t)r * D_;
        const float qpv = qp[r];
        a0 += qpv * wr[tid];
        a1 += qpv * wr[256 + tid];
        a2 += qpv * wr[512 + tid];
      }
      qkl[h*D_ +       tid] = a0 * 0.125f;
      qkl[h*D_ + 256 + tid] = a1 * 0.125f;
      qkl[h*D_ + 512 + tid] = a2 * 0.125f;
    }
  }
  __syncthreads();

  // ---- P3: scores[h][s=tid] = qk_h . kv_s (patch from L2) ----
  float acc[H_];
  #pragma unroll
  for (int h = 0; h < H_; ++h) acc[h] = 0.f;
  #pragma unroll
  for (int c = 0; c < 3; ++c) {
    const float* chp = xb + (size_t)(3*tid + c)*(W_*W_);
    for (int blk = 0; blk < 8; ++blk) {
      float4 v[8];
      #pragma unroll
      for (int u = 0; u < 8; ++u) {
        const int pg = blk*8 + u;
        v[u] = *(const float4*)(chp + (pg>>2)*W_ + (pg&3)*4);
      }
      const int dbase = c*256 + blk*32;
      #pragma unroll
      for (int h = 0; h < H_; ++h) {
        const float4* qh = (const float4*)(qkl + h*D_ + dbase);
        float s0 = 0.f;
        #pragma unroll
        for (int u = 0; u < 8; ++u) {
          const float4 qq = qh[u];
          s0 += qq.x*v[u].x + qq.y*v[u].y + qq.z*v[u].z + qq.w*v[u].w;
        }
        acc[h] += s0;
      }
    }
  }
  __syncthreads();                     // all qk reads done before aliasing
  float* sc = qkl;                     // sc[h][s] aliases qkl front (12 KB)
  #pragma unroll
  for (int h = 0; h < H_; ++h) sc[h*S_ + tid] = acc[h];
  __syncthreads();

  // ---- P4: softmax over s (3 heads per wave) ----
  {
    const int wv = tid >> 6, lane = tid & 63;
    #pragma unroll
    for (int hh = 0; hh < 3; ++hh) {
      const int h = wv*3 + hh;
      float4 v = *(const float4*)(&sc[h*S_ + lane*4]);
      float m = fmaxf(fmaxf(v.x, v.y), fmaxf(v.z, v.w));
      #pragma unroll
      for (int off = 32; off > 0; off >>= 1) m = fmaxf(m, __shfl_xor(m, off));
      const float e0 = __expf(v.x - m), e1 = __expf(v.y - m),
                  e2 = __expf(v.z - m), e3 = __expf(v.w - m);
      float ss = (e0+e1)+(e2+e3);
      #pragma unroll
      for (int off = 32; off > 0; off >>= 1) ss += __shfl_xor(ss, off);
      const float inv = 1.0f / ss;
      *(float4*)(&sc[h*S_ + lane*4]) = make_float4(e0*inv, e1*inv, e2*inv, e3*inv);
    }
  }
  __syncthreads();

  // ---- P5: w[h][c*256+p] = sum_s attn[h][s] * patch[3s+c][p], p = tid ----
  float wacc[H_][3];
  #pragma unroll
  for (int h = 0; h < H_; ++h) { wacc[h][0]=0.f; wacc[h][1]=0.f; wacc[h][2]=0.f; }
  const float* xp0 = xb + (tid>>4)*W_ + (tid&15);
  for (int s = 0; s < S_; ++s) {
    const float p0 = xp0[(size_t)(3*s+0)*(W_*W_)];
    const float p1 = xp0[(size_t)(3*s+1)*(W_*W_)];
    const float p2 = xp0[(size_t)(3*s+2)*(W_*W_)];
    #pragma unroll
    for (int h = 0; h < H_; ++h) {
      const float at = sc[h*S_ + s];
      wacc[h][0] += at*p0; wacc[h][1] += at*p1; wacc[h][2] += at*p2;
    }
  }
  float* wp = wout + (size_t)bt*H_*D_;
  #pragma unroll
  for (int h = 0; h < H_; ++h)
    #pragma unroll
    for (int c = 0; c < 3; ++c)
      wp[h*D_ + c*256 + tid] = wacc[h][c];
}

// K4a: ctx[bt][h*64+i] = sum_d w[bt][h][d] * Wv[h*64+i][d] + bv   (384 blocks)
__global__ __launch_bounds__(256) void k_ctx(const float* __restrict__ wbuf,
                                             const float* __restrict__ ipw,
                                             const float* __restrict__ ipb,
                                             float* __restrict__ ctx) {
  const int h = blockIdx.x >> 5;
  const int bt0 = (blockIdx.x & 31) * 16;
  const int tid = threadIdx.x;
  const float* Wv = ipw + (size_t)2*D_*D_ + (size_t)h*64*D_;
  __shared__ float wt[64][65];
  __shared__ float at[16][65];
  const int i = tid & 63, qw = tid >> 6;
  float acc[4] = {0,0,0,0};
  for (int dc = 0; dc < D_; dc += 64) {
    #pragma unroll
    for (int k = 0; k < 4; ++k) {
      const int idx = k*256 + tid;
      const int r = idx >> 4, c4 = idx & 15;
      *(float4*)&wt[r][c4*4] = *(const float4*)(Wv + (size_t)r*D_ + dc + c4*4);
    }
    {
      const int r = tid >> 4, c4 = tid & 15;
      *(float4*)&at[r][c4*4] = *(const float4*)(wbuf + ((size_t)(bt0 + r)*H_ + h)*D_ + dc + c4*4);
    }
    __syncthreads();
    #pragma unroll
    for (int dd = 0; dd < 64; ++dd) {
      const float wv = wt[i][dd];
      #pragma unroll
      for (int k = 0; k < 4; ++k)
        acc[k] += at[qw + k*4][dd] * wv;
    }
    __syncthreads();
  }
  const float bvv = ipb[2*D_ + h*64 + i];
  #pragma unroll
  for (int k = 0; k < 4; ++k)
    ctx[(size_t)(bt0 + qw + k*4)*D_ + h*64 + i] = acc[k] + bvv;
}

// K4b: out[bt][j] = sum_e ctx[bt][e] * ow[j][e] + ob[j]   (384 blocks)
__global__ __launch_bounds__(256) void k_out(const float* __restrict__ ctx,
                                             const float* __restrict__ ow,
                                             const float* __restrict__ ob,
                                             float* __restrict__ out) {
  const int jt = blockIdx.x >> 5;
  const int bt0 = (blockIdx.x & 31) * 16;
  const int tid = threadIdx.x;
  const float* Wr = ow + (size_t)jt*64*D_;
  __shared__ float wt[64][65];
  __shared__ float at[16][65];
  const int i = tid & 63, qw = tid >> 6;
  float acc[4] = {0,0,0,0};
  for (int dc = 0; dc < D_; dc += 64) {
    #pragma unroll
    for (int k = 0; k < 4; ++k) {
      const int idx = k*256 + tid;
      const int r = idx >> 4, c4 = idx & 15;
      *(float4*)&wt[r][c4*4] = *(const float4*)(Wr + (size_t)r*D_ + dc + c4*4);
    }
    {
      const int r = tid >> 4, c4 = tid & 15;
      *(float4*)&at[r][c4*4] = *(const float4*)(ctx + (size_t)(bt0 + r)*D_ + dc + c4*4);
    }
    __syncthreads();
    #pragma unroll
    for (int dd = 0; dd < 64; ++dd) {
      const float wv = wt[i][dd];
      #pragma unroll
      for (int k = 0; k < 4; ++k)
        acc[k] += at[qw + k*4][dd] * wv;
    }
    __syncthreads();
  }
  const float obv = ob[jt*64 + i];
  #pragma unroll
  for (int k = 0; k < 4; ++k)
    out[(size_t)(bt0 + qw + k*4)*D_ + jt*64 + i] = acc[k] + obv;
}

extern "C" void kernel_launch(void* const* d_in, const int* in_sizes, int n_in,
                              void* d_out, int out_size, void* d_ws, size_t ws_size,
                              hipStream_t stream) {
  const float* x   = (const float*)d_in[0];
  const float* ipw = (const float*)d_in[1];
  const float* ipb = (const float*)d_in[2];
  const float* ow  = (const float*)d_in[3];
  const float* ob  = (const float*)d_in[4];
  float* out = (float*)d_out;

  float* wb   = (float*)d_ws;                    // BT*H*D = 18.9 MB
  float* ctxb = wb + (size_t)BT_*H_*D_;          // BT*D   = 1.57 MB

  k_mega<<<dim3(BT_), dim3(256), 0, stream>>>(x, ipw, ipb, wb);
  k_ctx <<<dim3(384), dim3(256), 0, stream>>>(wb, ipw, ipb, ctxb);
  k_out <<<dim3(384), dim3(256), 0, stream>>>(ctxb, ow, ob, out);
}